// Round 1
// baseline (4839.131 us; speedup 1.0000x reference)
//
#include <hip/hip_runtime.h>

#define B_SZ 512
#define T_ENC 140
#define E_DIM 256
#define H_DIM 512
#define O_DIM 64
#define PRED 140
#define T_TOT 280

typedef short bf16x8 __attribute__((ext_vector_type(8)));
typedef float f32x4 __attribute__((ext_vector_type(4)));

static __device__ __forceinline__ unsigned short f2b(float x){
  union { float f; unsigned u; } v; v.f = x;
  unsigned r = v.u + 0x7fffu + ((v.u >> 16) & 1u);
  return (unsigned short)(r >> 16);
}
static __device__ __forceinline__ float sigmoidf_(float x){
  return 1.0f / (1.0f + __expf(-x));
}
static __device__ __forceinline__ float tanhf_(float x){
  float e2 = __expf(-2.0f * fabsf(x));
  float t = (1.0f - e2) / (1.0f + e2);
  return x < 0.0f ? -t : t;
}

__global__ void k_cast(const float* __restrict__ src, unsigned short* __restrict__ dst, int n){
  int i = blockIdx.x * 256 + threadIdx.x;
  if (i < n) dst[i] = f2b(src[i]);
}

// out_W (E x H) -> outWT16 (H x E) bf16
__global__ void k_transpose_cast(const float* __restrict__ src, unsigned short* __restrict__ dst){
  int i = blockIdx.x * 256 + threadIdx.x;   // over H*E = 131072
  int j = i >> 8;        // 0..511 row of dst
  int k = i & 255;       // 0..255
  dst[i] = f2b(src[k * H_DIM + j]);
}

__global__ void k_init_h(const float* __restrict__ eh, float* __restrict__ h, unsigned short* __restrict__ h16){
  int i = blockIdx.x * 256 + threadIdx.x;   // B*H
  float v = eh[i];
  h[i] = v; h16[i] = f2b(v);
}

__global__ void k_x0(const float* __restrict__ enc, unsigned short* __restrict__ x016){
  int i = blockIdx.x * 256 + threadIdx.x;   // B*E
  int b = i >> 8; int k = i & 255;
  x016[i] = f2b(enc[((size_t)b * T_ENC + (T_ENC - 1)) * E_DIM + k]);
}

// bias_big = [emb_b + emb_W@out_b (512) | b_hh (1536) | reg_b + reg_W@out_b (64)]
__global__ void k_bias(const float* __restrict__ embW, const float* __restrict__ emb_b,
                       const float* __restrict__ out_b, const float* __restrict__ b_hh,
                       const float* __restrict__ regW, const float* __restrict__ reg_b,
                       float* __restrict__ bias_big){
  int i = blockIdx.x * 256 + threadIdx.x;
  if (i < 512){
    float s = emb_b[i];
    for (int k = 0; k < 256; k++) s += embW[i * 256 + k] * out_b[k];
    bias_big[i] = s;
  } else if (i < 2048){
    bias_big[i] = b_hh[i - 512];
  } else if (i < 2112){
    int o = i - 2048;
    float s = reg_b[o];
    for (int k = 0; k < 256; k++) s += regW[o * 256 + k] * out_b[k];
    bias_big[i] = s;
  }
}

// Generic C = A @ W^T (+bias). A: M x K (bf16 or f32), W: N x K bf16 row-major.
// mode 0: f32 out (ldc); 1: bf16 out; 2: relu + bf16 out; 3: f32 out with encoder (b,t) row remap
__global__ __launch_bounds__(256)
void k_gemm(const void* __restrict__ Aptr, int a_is_f32,
            const unsigned short* __restrict__ W,
            const float* __restrict__ bias,
            void* __restrict__ Cptr, int mode,
            int M, int N, int K, int ldc)
{
  const int lane = threadIdx.x & 63;
  const int wave = threadIdx.x >> 6;
  const int ln = lane & 15;
  const int kq = lane >> 4;
  const int m0 = blockIdx.y * 64 + wave * 16;
  const int n0 = blockIdx.x * 64;

  f32x4 acc[4] = {};
  const int arow = m0 + ln;
  const unsigned short* wp = W + (size_t)(n0 + ln) * K + kq * 8;
  const int nk = K >> 5;

  if (a_is_f32){
    const float* ap = (const float*)Aptr + (size_t)arow * K + kq * 8;
    for (int t = 0; t < nk; ++t){
      f32x4 u0 = *(const f32x4*)(ap);
      f32x4 u1 = *(const f32x4*)(ap + 4);
      bf16x8 af;
      af[0] = (short)f2b(u0[0]); af[1] = (short)f2b(u0[1]);
      af[2] = (short)f2b(u0[2]); af[3] = (short)f2b(u0[3]);
      af[4] = (short)f2b(u1[0]); af[5] = (short)f2b(u1[1]);
      af[6] = (short)f2b(u1[2]); af[7] = (short)f2b(u1[3]);
      #pragma unroll
      for (int j = 0; j < 4; j++){
        bf16x8 wf = *(const bf16x8*)(wp + (size_t)(16 * j) * K);
        acc[j] = __builtin_amdgcn_mfma_f32_16x16x32_bf16(af, wf, acc[j], 0, 0, 0);
      }
      ap += 32; wp += 32;
    }
  } else {
    const unsigned short* ap = (const unsigned short*)Aptr + (size_t)arow * K + kq * 8;
    for (int t = 0; t < nk; ++t){
      bf16x8 af = *(const bf16x8*)ap;
      #pragma unroll
      for (int j = 0; j < 4; j++){
        bf16x8 wf = *(const bf16x8*)(wp + (size_t)(16 * j) * K);
        acc[j] = __builtin_amdgcn_mfma_f32_16x16x32_bf16(af, wf, acc[j], 0, 0, 0);
      }
      ap += 32; wp += 32;
    }
  }

  #pragma unroll
  for (int j = 0; j < 4; j++){
    int col = n0 + 16 * j + ln;
    float bv = bias ? bias[col] : 0.0f;
    #pragma unroll
    for (int r = 0; r < 4; r++){
      int orow = m0 + kq * 4 + r;
      float v = acc[j][r] + bv;
      if (mode == 0){
        ((float*)Cptr)[(size_t)orow * ldc + col] = v;
      } else if (mode == 1){
        ((unsigned short*)Cptr)[(size_t)orow * ldc + col] = f2b(v);
      } else if (mode == 2){
        ((unsigned short*)Cptr)[(size_t)orow * ldc + col] = f2b(v > 0.f ? v : 0.f);
      } else {
        int bb = orow / T_ENC;
        int tt = orow - bb * T_ENC;
        ((float*)Cptr)[((size_t)bb * T_TOT + tt) * O_DIM + col] = v;
      }
    }
  }
}

// P1: T = h16 @ Wbig^T + bias_big.  cols [0,512): e=relu -> bf16; [512,2048): gh f32; [2048,2112): y_s -> d_out
__global__ __launch_bounds__(256)
void k_step_p1(const unsigned short* __restrict__ h16,
               const unsigned short* __restrict__ Wbig,
               const float* __restrict__ bias_big,
               unsigned short* __restrict__ e16,
               float* __restrict__ gh,
               float* __restrict__ out,
               int s)
{
  const int lane = threadIdx.x & 63;
  const int wave = threadIdx.x >> 6;
  const int ln = lane & 15;
  const int kq = lane >> 4;
  const int m0 = blockIdx.y * 64 + wave * 16;
  const int n0 = blockIdx.x * 64;
  f32x4 acc[4] = {};
  const unsigned short* ap = h16 + (size_t)(m0 + ln) * H_DIM + kq * 8;
  const unsigned short* wp = Wbig + (size_t)(n0 + ln) * H_DIM + kq * 8;
  for (int t = 0; t < 16; ++t){
    bf16x8 af = *(const bf16x8*)ap;
    #pragma unroll
    for (int j = 0; j < 4; j++){
      bf16x8 wf = *(const bf16x8*)(wp + (size_t)(16 * j) * H_DIM);
      acc[j] = __builtin_amdgcn_mfma_f32_16x16x32_bf16(af, wf, acc[j], 0, 0, 0);
    }
    ap += 32; wp += 32;
  }
  #pragma unroll
  for (int j = 0; j < 4; j++){
    int col = n0 + 16 * j + ln;
    float bv = bias_big[col];
    #pragma unroll
    for (int r = 0; r < 4; r++){
      int b = m0 + kq * 4 + r;
      float v = acc[j][r] + bv;
      if (col < 512){
        e16[(size_t)b * H_DIM + col] = f2b(v > 0.f ? v : 0.f);
      } else if (col < 2048){
        gh[(size_t)b * 1536 + (col - 512)] = v;
      } else {
        out[((size_t)b * T_TOT + T_ENC + s) * O_DIM + (col - 2048)] = v;
      }
    }
  }
}

// P2: gi = e16 @ w_ih^T (3 gates per wave tile) + GRU gate epilogue -> h (in place), h16
__global__ __launch_bounds__(256)
void k_step_p2(const unsigned short* __restrict__ e16,
               const unsigned short* __restrict__ wih16,
               const float* __restrict__ b_ih,
               const float* __restrict__ gh,
               float* __restrict__ h,
               unsigned short* __restrict__ h16)
{
  const int lane = threadIdx.x & 63;
  const int wave = threadIdx.x >> 6;
  const int ln = lane & 15;
  const int kq = lane >> 4;
  const int m0 = blockIdx.y * 64 + wave * 16;
  const int j0 = blockIdx.x * 16;
  f32x4 aR = {}, aZ = {}, aN = {};
  const unsigned short* ap  = e16  + (size_t)(m0 + ln) * H_DIM + kq * 8;
  const unsigned short* wpR = wih16 + (size_t)(j0 + ln) * H_DIM + kq * 8;
  const unsigned short* wpZ = wpR + (size_t)512 * H_DIM;
  const unsigned short* wpN = wpR + (size_t)1024 * H_DIM;
  for (int t = 0; t < 16; ++t){
    bf16x8 af = *(const bf16x8*)ap;
    aR = __builtin_amdgcn_mfma_f32_16x16x32_bf16(af, *(const bf16x8*)wpR, aR, 0, 0, 0);
    aZ = __builtin_amdgcn_mfma_f32_16x16x32_bf16(af, *(const bf16x8*)wpZ, aZ, 0, 0, 0);
    aN = __builtin_amdgcn_mfma_f32_16x16x32_bf16(af, *(const bf16x8*)wpN, aN, 0, 0, 0);
    ap += 32; wpR += 32; wpZ += 32; wpN += 32;
  }
  const int j = j0 + ln;
  const float bR = b_ih[j], bZ = b_ih[512 + j], bN = b_ih[1024 + j];
  #pragma unroll
  for (int r = 0; r < 4; r++){
    int b = m0 + kq * 4 + r;
    const float* ghrow = gh + (size_t)b * 1536;
    float rg = sigmoidf_(aR[r] + bR + ghrow[j]);
    float z  = sigmoidf_(aZ[r] + bZ + ghrow[512 + j]);
    float nn = tanhf_(aN[r] + bN + rg * ghrow[1024 + j]);
    float hv = (1.f - z) * nn + z * h[(size_t)b * H_DIM + j];
    h[(size_t)b * H_DIM + j] = hv;
    h16[(size_t)b * H_DIM + j] = f2b(hv);
  }
}

extern "C" void kernel_launch(void* const* d_in, const int* in_sizes, int n_in,
                              void* d_out, int out_size, void* d_ws, size_t ws_size,
                              hipStream_t stream)
{
  const float* enc   = (const float*)d_in[0];
  const float* ehid  = (const float*)d_in[1];
  const float* embW  = (const float*)d_in[2];
  const float* emb_b = (const float*)d_in[3];
  const float* w_ih  = (const float*)d_in[4];
  const float* w_hh  = (const float*)d_in[5];
  const float* b_ih  = (const float*)d_in[6];
  const float* b_hh  = (const float*)d_in[7];
  const float* out_W = (const float*)d_in[8];
  const float* out_b = (const float*)d_in[9];
  const float* reg_W = (const float*)d_in[10];
  const float* reg_b = (const float*)d_in[11];
  float* out = (float*)d_out;

  char* ws = (char*)d_ws;
  size_t off = 0;
  auto alloc = [&](size_t bytes)->char*{
    char* p = ws + off; off += (bytes + 255) & ~(size_t)255; return p;
  };
  unsigned short* Wbig    = (unsigned short*)alloc((size_t)2112 * 512 * 2);
  unsigned short* wih16   = (unsigned short*)alloc((size_t)1536 * 512 * 2);
  unsigned short* embW16  = (unsigned short*)alloc((size_t)512 * 256 * 2);
  unsigned short* regW16  = (unsigned short*)alloc((size_t)64 * 256 * 2);
  unsigned short* outWT16 = (unsigned short*)alloc((size_t)512 * 256 * 2);
  float*          bias_big= (float*)alloc((size_t)2112 * 4);
  unsigned short* e16     = (unsigned short*)alloc((size_t)512 * 512 * 2);
  float*          gh      = (float*)alloc((size_t)512 * 1536 * 4);
  float*          h       = (float*)alloc((size_t)512 * 512 * 4);
  unsigned short* h16     = (unsigned short*)alloc((size_t)512 * 512 * 2);
  unsigned short* x016    = (unsigned short*)alloc((size_t)512 * 256 * 2);

  // ---- precompute (runs every call; ws is re-poisoned) ----
  k_cast<<<(1536 * 512) / 256, 256, 0, stream>>>(w_ih, wih16, 1536 * 512);
  k_cast<<<(1536 * 512) / 256, 256, 0, stream>>>(w_hh, Wbig + (size_t)512 * 512, 1536 * 512);
  k_cast<<<(512 * 256) / 256, 256, 0, stream>>>(embW, embW16, 512 * 256);
  k_cast<<<(64 * 256) / 256, 256, 0, stream>>>(reg_W, regW16, 64 * 256);
  k_transpose_cast<<<512, 256, 0, stream>>>(out_W, outWT16);
  k_bias<<<9, 256, 0, stream>>>(embW, emb_b, out_b, b_hh, reg_W, reg_b, bias_big);
  k_init_h<<<(512 * 512) / 256, 256, 0, stream>>>(ehid, h, h16);
  k_x0<<<(512 * 256) / 256, 256, 0, stream>>>(enc, x016);

  // W_comb = emb_W @ out_W  -> Wbig rows [0,512)
  k_gemm<<<dim3(8, 8), 256, 0, stream>>>(embW, 1, outWT16, nullptr, Wbig, 1, 512, 512, 256, 512);
  // W_or = reg_W @ out_W  -> Wbig rows [2048,2112)
  k_gemm<<<dim3(8, 1), 256, 0, stream>>>(reg_W, 1, outWT16, nullptr, Wbig + (size_t)2048 * 512, 1, 64, 512, 256, 512);
  // e0 = relu(x0 @ emb_W^T + emb_b)
  k_gemm<<<dim3(8, 8), 256, 0, stream>>>(x016, 0, embW16, emb_b, e16, 2, 512, 512, 256, 512);
  // gh0 = h0 @ w_hh^T + b_hh
  k_gemm<<<dim3(24, 8), 256, 0, stream>>>(h16, 0, Wbig + (size_t)512 * 512, b_hh, gh, 0, 512, 1536, 512, 1536);
  // encoder projection: out[:, 0:140, :] = enc @ reg_W^T + reg_b
  k_gemm<<<dim3(1, 1120), 256, 0, stream>>>(enc, 1, regW16, reg_b, out, 3, 71680, 64, 256, 0);

  // ---- 140 sequential GRU steps, 2 kernels each ----
  for (int s = 0; s < 140; ++s){
    k_step_p2<<<dim3(32, 8), 256, 0, stream>>>(e16, wih16, b_ih, gh, h, h16);
    k_step_p1<<<dim3(33, 8), 256, 0, stream>>>(h16, Wbig, bias_big, e16, gh, out, s);
  }
}